// Round 8
// baseline (808.598 us; speedup 1.0000x reference)
//
#include <hip/hip_runtime.h>
#include <stdint.h>

#define NB 64
#define NO 32
#define NI 512
#define ND 64

typedef __attribute__((ext_vector_type(8))) short short8;
typedef __attribute__((ext_vector_type(4))) float f32x4;

// async global->LDS DMA, 16 B/lane. Global addr per-lane; LDS base wave-uniform,
// lane i lands at base + 16*i (m104/m108 semantics).
#define GL2LDS(g, s) __builtin_amdgcn_global_load_lds( \
    (const __attribute__((address_space(1))) void*)(g), \
    (__attribute__((address_space(3))) void*)(s), 16, 0, 0)

__device__ __forceinline__ float blo(unsigned int u) {
    union { unsigned int i; float f; } v; v.i = u << 16; return v.f;
}
__device__ __forceinline__ float bhi(unsigned int u) {
    union { unsigned int i; float f; } v; v.i = u & 0xFFFF0000u; return v.f;
}
__device__ __forceinline__ unsigned short f2bf(float f) {
    union { float f; unsigned int i; } v; v.f = f;
    return (unsigned short)((v.i + 0x7FFFu + ((v.i >> 16) & 1u)) >> 16);
}
__device__ __forceinline__ short8 pack8(const float4 a, const float4 b) {
    short8 r;
    r[0] = (short)f2bf(a.x); r[1] = (short)f2bf(a.y);
    r[2] = (short)f2bf(a.z); r[3] = (short)f2bf(a.w);
    r[4] = (short)f2bf(b.x); r[5] = (short)f2bf(b.y);
    r[6] = (short)f2bf(b.z); r[7] = (short)f2bf(b.w);
    return r;
}
__device__ __forceinline__ void ld_a(float4 r[4], const float* __restrict__ p) {
    r[0] = *(const float4*)(p);
    r[1] = *(const float4*)(p + 4);
    r[2] = *(const float4*)(p + 32);
    r[3] = *(const float4*)(p + 36);
}

// K1: x_hat = W x, bf16, layout xh[b][i][o][d'] with PERMUTED d-order
// d' = 4c + td (d = 16 td + c). o,d' innermost. Also accumulates
// s0[b][o][d'] = sum_i x_hat (fp32 atomic partials; measured free -- kernel
// latency-bound with slack), replacing the entire route<0> pass. UNCHANGED
// (control: ~205 us, FETCH 164 MB, WRITE 262 MB).
__global__ __launch_bounds__(256) void k_gemm(const float* __restrict__ x,
                                              const float* __restrict__ w,
                                              unsigned short* __restrict__ xh,
                                              float* __restrict__ s0) {
    __shared__ float Wl[3][4096];            // 48 KB, triple-buffered W tiles
    const int o  = blockIdx.x & 31;
    const int ig = blockIdx.x >> 5;
    const int t  = threadIdx.x;
    const int wv = t >> 6;
    const int l  = t & 63;
    const int q  = l >> 4;
    const int c  = l & 15;

    const float* wbase = w + ((size_t)o * NI + ig * 8) * 4096;

    auto stage = [&](int buf, int ii) {
        const float* src = wbase + (size_t)ii * 4096;
        #pragma unroll
        for (int k = 0; k < 4; ++k) {
            const int s = wv * 256 + k * 64 + l;
            const int r = s >> 4;
            const int g = (s & 15) ^ (r & 15);
            GL2LDS(src + r * 64 + g * 4, &Wl[buf][(wv * 256 + k * 64) * 4]);
        }
    };

    const float* ap0 = x + ((size_t)(16 * wv + c) * NI + ig * 8) * 64 + q * 8;
    float4 ra[4], na[4];
    ld_a(ra, ap0);
    stage(0, 0);
    stage(1, 1);

    f32x4 psum[4];
    #pragma unroll
    for (int td = 0; td < 4; ++td) psum[td] = (f32x4){0.f, 0.f, 0.f, 0.f};

    uint2 cst[4];
    #pragma unroll
    for (int ii = 0; ii < 8; ++ii) {
        __syncthreads();
        if (ii > 0) {
            #pragma unroll
            for (int rr = 0; rr < 4; ++rr) {
                const int bq = 16 * wv + 4 * q + rr;
                *(uint2*)(xh + (((size_t)bq * NI + (ig * 8 + ii - 1)) * NO + o) * ND + 4 * c) = cst[rr];
            }
        }
        if (ii < 6) stage((ii + 2) % 3, ii + 2);
        if (ii < 7) ld_a(na, ap0 + (ii + 1) * 64);

        const float* Wb = Wl[ii % 3];
        const short8 a0 = pack8(ra[0], ra[1]);
        const short8 a1 = pack8(ra[2], ra[3]);
        f32x4 acc[4];
        #pragma unroll
        for (int td = 0; td < 4; ++td) {
            const int r = 16 * td + c;
            const float4 f0 = *(const float4*)&Wb[(r * 16 + ((2 * q)     ^ c)) * 4];
            const float4 f1 = *(const float4*)&Wb[(r * 16 + ((2 * q + 1) ^ c)) * 4];
            const float4 f2 = *(const float4*)&Wb[(r * 16 + ((2 * q + 8) ^ c)) * 4];
            const float4 f3 = *(const float4*)&Wb[(r * 16 + ((2 * q + 9) ^ c)) * 4];
            const short8 b0 = pack8(f0, f1);
            const short8 b1 = pack8(f2, f3);
            f32x4 z = {0.f, 0.f, 0.f, 0.f};
            z = __builtin_amdgcn_mfma_f32_16x16x32_bf16(a0, b0, z, 0, 0, 0);
            z = __builtin_amdgcn_mfma_f32_16x16x32_bf16(a1, b1, z, 0, 0, 0);
            acc[td] = z;
            psum[td] += z;
        }
        #pragma unroll
        for (int rr = 0; rr < 4; ++rr) {
            cst[rr].x = (unsigned int)f2bf(acc[0][rr]) | ((unsigned int)f2bf(acc[1][rr]) << 16);
            cst[rr].y = (unsigned int)f2bf(acc[2][rr]) | ((unsigned int)f2bf(acc[3][rr]) << 16);
        }
        #pragma unroll
        for (int j = 0; j < 4; ++j) ra[j] = na[j];
    }
    #pragma unroll
    for (int rr = 0; rr < 4; ++rr) {
        const int bq = 16 * wv + 4 * q + rr;
        *(uint2*)(xh + (((size_t)bq * NI + (ig * 8 + 7)) * NO + o) * ND + 4 * c) = cst[rr];
    }
    #pragma unroll
    for (int rr = 0; rr < 4; ++rr) {
        const int bq = 16 * wv + 4 * q + rr;
        float* sp = s0 + ((size_t)bq * NO + o) * ND + 4 * c;
        #pragma unroll
        for (int td = 0; td < 4; ++td) atomicAdd(sp + td, psum[td][rr]);
    }
}

// Squash s -> out, update osum. One wave per (b,o) row of 64 d'-elements.
// STEP 0: s = s0 (atomic-built, scale 1/32), osum = out.
// STEP 1: s = s_part[b][16][o][d'], reduce 16 partials, osum += out.
// STEP 2: same reduce, final output with d' -> d remap.
template<int STEP>
__global__ __launch_bounds__(256) void k_sq(const float* __restrict__ s,
                                            float* __restrict__ osum,
                                            float* __restrict__ outp) {
    const int t = threadIdx.x;
    const int wid = blockIdx.x * 4 + (t >> 6);   // = b*32 + o
    const int l = t & 63;                        // = d'
    float sv;
    if (STEP == 0) {
        sv = s[(size_t)wid * ND + l] * 0.03125f;
    } else {
        const int b = wid >> 5, o = wid & 31;
        const float* p = s + (((size_t)b * 16) * NO + o) * ND + l;
        sv = 0.f;
        #pragma unroll
        for (int ic = 0; ic < 16; ++ic) sv += p[(size_t)ic * NO * ND];
    }
    float s2 = sv * sv;
    #pragma unroll
    for (int m = 1; m < 64; m <<= 1) s2 += __shfl_xor(s2, m);
    const float n = sqrtf(s2);
    const float ov = sv * (s2 / (1.0f + s2)) / (n + 1e-8f);
    if (STEP == 0) osum[(size_t)wid * ND + l] = ov;
    if (STEP == 1) osum[(size_t)wid * ND + l] += ov;
    if (STEP == 2) outp[(size_t)wid * ND + 16 * (l & 3) + (l >> 2)] = ov;
}

// Routing pass. ROUND-8 SINGLE-VARIABLE CHANGE vs r7: block->address mapping
// is now B-FASTEST (consecutive blockIdx -> 2 MiB apart), replicating the old
// 85-us k_route's dispersion. r7's probe proved the ~190-us cost lives in the
// load path with ic-fastest mapping (co-scheduled blocks on 8 XCDs all hit the
// same contiguous 512 KiB -> concentrated channel/slice pressure). Everything
// else byte-identical to r7.
__global__ __launch_bounds__(256, 4) void k_rt(const unsigned short* __restrict__ xh,
                                               const float* __restrict__ osum,
                                               float* __restrict__ s_part) {
    __shared__ unsigned short tile[8 * 2048];    // 32 KB: 8 rows x [o][d']
    __shared__ float pS[NO][16];
    __shared__ float mS[16];
    __shared__ float zS[16];
    const int t  = threadIdx.x;
    const int b  = blockIdx.x & 63;              // b FASTEST (was blk>>4)
    const int ic = blockIdx.x >> 6;              // ic 0..15   (was blk&15)
    const int wv = t >> 6;
    const int l  = t & 63;
    const int o  = t >> 3;
    const int dg = t & 7;

    const float* op = osum + ((size_t)b * NO + o) * ND + dg * 8;
    float os[8];
    *(float4*)&os[0] = *(const float4*)op;
    *(float4*)&os[4] = *(const float4*)(op + 4);

    float sc[8] = {0, 0, 0, 0, 0, 0, 0, 0};

    for (int ch = 0; ch < 2; ++ch) {
        const int i0 = ic * 32 + ch * 16;
        // register half: rows i0+8 .. i0+15 (issued first, latency overlapped)
        uint4 rw[8];
        #pragma unroll
        for (int k = 0; k < 8; ++k)
            rw[k] = *(const uint4*)(xh + (((size_t)b * NI + i0 + 8 + k) * NO + o) * ND + dg * 8);
        // DMA half: rows i0 .. i0+7 (contiguous 32 KB), wave wv covers 8 KB
        {
            const unsigned short* gld = xh + ((size_t)b * NI + i0) * (NO * ND);
            #pragma unroll
            for (int k = 0; k < 8; ++k)
                GL2LDS(gld + wv * 4096 + k * 512 + l * 8, tile + wv * 4096 + k * 512);
        }
        __syncthreads();                         // DMA visible (drains vmcnt)

        // pull LDS rows to regs (1 KiB/wave contiguous, conflict-free)
        uint4 rl[8];
        #pragma unroll
        for (int ii = 0; ii < 8; ++ii)
            rl[ii] = *(const uint4*)(tile + ii * 2048 + o * 64 + dg * 8);

        // logits: 8-local dot + 3-level shfl tree over dg
        float pp[16];
        #pragma unroll
        for (int ii = 0; ii < 16; ++ii) {
            const uint4 r4v = (ii < 8) ? rl[ii] : rw[ii - 8];
            float a = blo(r4v.x) * os[0] + bhi(r4v.x) * os[1]
                    + blo(r4v.y) * os[2] + bhi(r4v.y) * os[3]
                    + blo(r4v.z) * os[4] + bhi(r4v.z) * os[5]
                    + blo(r4v.w) * os[6] + bhi(r4v.w) * os[7];
            a += __shfl_xor(a, 1);
            a += __shfl_xor(a, 2);
            a += __shfl_xor(a, 4);
            pp[ii] = a;
        }
        if (dg == 0) {
            #pragma unroll
            for (int ii = 0; ii < 16; ii += 4) {
                float4 v; v.x = pp[ii]; v.y = pp[ii + 1]; v.z = pp[ii + 2]; v.w = pp[ii + 3];
                *(float4*)&pS[o][ii] = v;
            }
        }
        __syncthreads();                         // pS visible

        // softmax stats over o per i-column (redundant compute, 16 write)
        {
            const int ii = t & 15;
            float m = pS[0][ii];
            #pragma unroll
            for (int oo = 1; oo < NO; ++oo) m = fmaxf(m, pS[oo][ii]);
            float Z = 0.f;
            #pragma unroll
            for (int oo = 0; oo < NO; ++oo) Z += __expf(pS[oo][ii] - m);
            if (t < 16) { mS[ii] = m; zS[ii] = 1.0f / Z; }
        }
        __syncthreads();                         // mS/zS visible; all dots done
                                                 // -> next chunk may re-DMA tile

        // c-weighted accumulation (regs only; no LDS reads here)
        #pragma unroll
        for (int ii = 0; ii < 16; ++ii) {
            const uint4 r4v = (ii < 8) ? rl[ii] : rw[ii - 8];
            const float cw = __expf(pp[ii] - mS[ii]) * zS[ii];
            sc[0] += cw * blo(r4v.x); sc[1] += cw * bhi(r4v.x);
            sc[2] += cw * blo(r4v.y); sc[3] += cw * bhi(r4v.y);
            sc[4] += cw * blo(r4v.z); sc[5] += cw * bhi(r4v.z);
            sc[6] += cw * blo(r4v.w); sc[7] += cw * bhi(r4v.w);
        }
    }

    // one dense store per thread: s_part[b][ic][o][d']
    float* sp = s_part + (((size_t)b * 16 + ic) * NO + o) * ND + dg * 8;
    #pragma unroll
    for (int j = 0; j < 4; ++j) ((float2*)sp)[j] = (float2){sc[2 * j], sc[2 * j + 1]};
}

// Diagnostic probe, ROUND-8 ARM B: identical load pattern to r7's probe
// (16 uint4/thread, 16 rows, 64 KiB/block) but with B-FASTEST block mapping.
// r7 measured arm A (ic-fastest) at ~190 us. If this drops to ~90-110 us the
// dispersion theory is confirmed; if it stays ~190 the mapping is exonerated.
__global__ __launch_bounds__(256) void k_probe(const unsigned short* __restrict__ xh,
                                               uint4* __restrict__ sink) {
    const int t  = threadIdx.x;
    const int b  = blockIdx.x & 63;              // b FASTEST (was blk>>5)
    const int ic = blockIdx.x >> 6;              // ic 0..31   (was blk&31)
    const int o  = t >> 3;
    const int dg = t & 7;
    const unsigned short* src = xh + (((size_t)b * NI + ic * 16) * NO + o) * ND + dg * 8;
    uint4 acc = {0, 0, 0, 0};
    #pragma unroll
    for (int ii = 0; ii < 16; ++ii) {
        const uint4 v = *(const uint4*)(src + (size_t)ii * NO * ND);
        acc.x ^= v.x; acc.y ^= v.y; acc.z ^= v.z; acc.w ^= v.w;
    }
    sink[(size_t)blockIdx.x * 256 + t] = acc;
}

extern "C" void kernel_launch(void* const* d_in, const int* in_sizes, int n_in,
                              void* d_out, int out_size, void* d_ws, size_t ws_size,
                              hipStream_t stream) {
    const float* x = (const float*)d_in[0];        // [64,512,64] fp32
    const float* w = (const float*)d_in[1];        // [32,512,64,64] fp32
    float* outp = (float*)d_out;                   // [64,32,64] fp32

    char* ws = (char*)d_ws;
    unsigned short* xh = (unsigned short*)ws;                    // 128 MiB bf16 xh[b][i][o][d']
    float* s0     = (float*)(ws + (size_t)134217728);            // 512 KiB [b][o][d'] (gemm atomics)
    float* s_part = (float*)(ws + (size_t)134217728 + 524288);   // 8 MiB [b][16][o][d']
    float* osum   = (float*)(ws + (size_t)134217728 + 524288 + 8388608); // 512 KiB

    hipMemsetAsync(s0, 0, 524288, stream);         // zero gemm's atomic accumulator
    k_gemm<<<dim3(2048), dim3(256), 0, stream>>>(x, w, xh, s0);
    k_sq<0><<<dim3(512), dim3(256), 0, stream>>>(s0, osum, nullptr);
    k_rt<<<dim3(1024), dim3(256), 0, stream>>>(xh, osum, s_part);
    k_sq<1><<<dim3(512), dim3(256), 0, stream>>>(s_part, osum, nullptr);
    k_rt<<<dim3(1024), dim3(256), 0, stream>>>(xh, osum, s_part);
    k_sq<2><<<dim3(512), dim3(256), 0, stream>>>(s_part, osum, outp);
    k_probe<<<dim3(2048), dim3(256), 0, stream>>>(xh, (uint4*)s_part);
}

// Round 10
// 462.759 us; speedup vs baseline: 1.7473x; 1.7473x over previous
//
#include <hip/hip_runtime.h>
#include <stdint.h>

#define NB 64
#define NO 32
#define NI 512
#define ND 64

typedef __attribute__((ext_vector_type(8))) short short8;
typedef __attribute__((ext_vector_type(4))) float f32x4;

// async global->LDS DMA, 16 B/lane. Global addr per-lane; LDS base wave-uniform,
// lane i lands at base + 16*i (m104/m108 semantics).
#define GL2LDS(g, s) __builtin_amdgcn_global_load_lds( \
    (const __attribute__((address_space(1))) void*)(g), \
    (__attribute__((address_space(3))) void*)(s), 16, 0, 0)

__device__ __forceinline__ float blo(unsigned int u) {
    union { unsigned int i; float f; } v; v.i = u << 16; return v.f;
}
__device__ __forceinline__ float bhi(unsigned int u) {
    union { unsigned int i; float f; } v; v.i = u & 0xFFFF0000u; return v.f;
}
__device__ __forceinline__ unsigned short f2bf(float f) {
    union { float f; unsigned int i; } v; v.f = f;
    return (unsigned short)((v.i + 0x7FFFu + ((v.i >> 16) & 1u)) >> 16);
}
__device__ __forceinline__ short8 pack8(const float4 a, const float4 b) {
    short8 r;
    r[0] = (short)f2bf(a.x); r[1] = (short)f2bf(a.y);
    r[2] = (short)f2bf(a.z); r[3] = (short)f2bf(a.w);
    r[4] = (short)f2bf(b.x); r[5] = (short)f2bf(b.y);
    r[6] = (short)f2bf(b.z); r[7] = (short)f2bf(b.w);
    return r;
}
__device__ __forceinline__ void ld_a(float4 r[4], const float* __restrict__ p) {
    r[0] = *(const float4*)(p);
    r[1] = *(const float4*)(p + 4);
    r[2] = *(const float4*)(p + 32);
    r[3] = *(const float4*)(p + 36);
}

// K1: x_hat = W x, stored bf16 in PERMUTED d-order: d' = 4c + td (d = 16 td + c).
// Layout xh[o][b][i][d'] (round-0 verified). T4 counted-vmcnt change:
// __syncthreads() emitted s_waitcnt vmcnt(0) -> drained the just-issued
// prefetch stage every iteration (triple-buffer defeated). Replaced with
// s_waitcnt vmcnt(8) + raw s_barrier. Steady-state safety (any emitted order):
// each iter issues 12 vmem ops (4 C-stores + 4 stage + 4 x-loads); stage(ii)
// is >=12 ops old at top of iter ii, so keeping only the 8 newest always
// completes it. ROUND-10 FIX: one-time prologue s_waitcnt vmcnt(0) -- at ii=0
// only 12 ops are outstanding and stage(0) could land among the kept 8
// (first-iteration race found by audit after r9's container failure).
__global__ __launch_bounds__(256) void k_gemm(const float* __restrict__ x,
                                              const float* __restrict__ w,
                                              unsigned short* __restrict__ xh) {
    __shared__ float Wl[3][4096];            // 48 KB, triple-buffered W tiles
    const int o  = blockIdx.x & 31;
    const int ig = blockIdx.x >> 5;
    const int t  = threadIdx.x;
    const int wv = t >> 6;
    const int l  = t & 63;
    const int q  = l >> 4;
    const int c  = l & 15;

    const float* wbase = w + ((size_t)o * NI + ig * 8) * 4096;

    auto stage = [&](int buf, int ii) {
        const float* src = wbase + (size_t)ii * 4096;
        #pragma unroll
        for (int k = 0; k < 4; ++k) {
            const int s = wv * 256 + k * 64 + l;
            const int r = s >> 4;
            const int g = (s & 15) ^ (r & 15);
            GL2LDS(src + r * 64 + g * 4, &Wl[buf][(wv * 256 + k * 64) * 4]);
        }
    };

    const float* ap0 = x + ((size_t)(16 * wv + c) * NI + ig * 8) * 64 + q * 8;
    float4 ra[4], na[4];
    ld_a(ra, ap0);
    stage(0, 0);
    stage(1, 1);
    // prologue drain: stage(0) (and stage(1)) guaranteed in LDS before ii=0.
    asm volatile("s_waitcnt vmcnt(0)" ::: "memory");

    uint2 cst[4];
    #pragma unroll 1
    for (int ii = 0; ii < 8; ++ii) {
        // counted drain: completes stage(ii) (>=12 ops back in steady state);
        // keeps the 8 newest vmem ops (next stage + x prefetch) in flight.
        asm volatile("s_waitcnt vmcnt(8)" ::: "memory");
        __builtin_amdgcn_s_barrier();
        if (ii > 0) {                        // store iter ii-1's C
            #pragma unroll
            for (int rr = 0; rr < 4; ++rr) {
                const int bq = 16 * wv + 4 * q + rr;
                *(uint2*)(xh + (((size_t)o * NB + bq) * NI + (ig * 8 + ii - 1)) * ND + 4 * c) = cst[rr];
            }
        }
        if (ii < 6) stage((ii + 2) % 3, ii + 2);
        if (ii < 7) ld_a(na, ap0 + (ii + 1) * 64);

        const float* Wb = Wl[ii % 3];
        const short8 a0 = pack8(ra[0], ra[1]);
        const short8 a1 = pack8(ra[2], ra[3]);
        f32x4 acc[4];
        #pragma unroll
        for (int td = 0; td < 4; ++td) {
            const int r = 16 * td + c;
            const float4 f0 = *(const float4*)&Wb[(r * 16 + ((2 * q)     ^ c)) * 4];
            const float4 f1 = *(const float4*)&Wb[(r * 16 + ((2 * q + 1) ^ c)) * 4];
            const float4 f2 = *(const float4*)&Wb[(r * 16 + ((2 * q + 8) ^ c)) * 4];
            const float4 f3 = *(const float4*)&Wb[(r * 16 + ((2 * q + 9) ^ c)) * 4];
            const short8 b0 = pack8(f0, f1);
            const short8 b1 = pack8(f2, f3);
            f32x4 z = {0.f, 0.f, 0.f, 0.f};
            z = __builtin_amdgcn_mfma_f32_16x16x32_bf16(a0, b0, z, 0, 0, 0);
            z = __builtin_amdgcn_mfma_f32_16x16x32_bf16(a1, b1, z, 0, 0, 0);
            acc[td] = z;
        }
        #pragma unroll
        for (int rr = 0; rr < 4; ++rr) {
            cst[rr].x = (unsigned int)f2bf(acc[0][rr]) | ((unsigned int)f2bf(acc[1][rr]) << 16);
            cst[rr].y = (unsigned int)f2bf(acc[2][rr]) | ((unsigned int)f2bf(acc[2][rr]) << 16);
        }
        // NOTE: line above must pack acc[2]/acc[3] -- fixed below (kept comment
        // to flag the audit; see corrected packing)
        #pragma unroll
        for (int rr = 0; rr < 4; ++rr) {
            cst[rr].x = (unsigned int)f2bf(acc[0][rr]) | ((unsigned int)f2bf(acc[1][rr]) << 16);
            cst[rr].y = (unsigned int)f2bf(acc[2][rr]) | ((unsigned int)f2bf(acc[3][rr]) << 16);
        }
        #pragma unroll
        for (int j = 0; j < 4; ++j) ra[j] = na[j];
    }
    #pragma unroll
    for (int rr = 0; rr < 4; ++rr) {         // last iteration's C
        const int bq = 16 * wv + 4 * q + rr;
        *(uint2*)(xh + (((size_t)o * NB + bq) * NI + (ig * 8 + 7)) * ND + 4 * c) = cst[rr];
    }
}

// Softmax stats per (b,i): m = max_o logits, 1/Z. 128 blocks. (round-0 verified)
__global__ __launch_bounds__(256) void k_soft(const float* __restrict__ b_in,
                                              float* __restrict__ mz) {
    const int p = blockIdx.x * 256 + threadIdx.x;        // p = b*512 + i
    const int b = p >> 9, i = p & 511;
    const float* bp = b_in + (size_t)b * NO * NI + i;
    float v[NO];
    #pragma unroll
    for (int oo = 0; oo < NO; ++oo) v[oo] = bp[(size_t)oo * NI];
    float m = v[0];
    #pragma unroll
    for (int oo = 1; oo < NO; ++oo) m = fmaxf(m, v[oo]);
    float Z = 0.f;
    #pragma unroll
    for (int oo = 0; oo < NO; ++oo) Z += __expf(v[oo] - m);
    mz[p] = m;
    mz[NB * NI + p] = 1.0f / Z;
}

// Routing step, block = (b,o). Hybrid tile: rows 0..255 DMA'd to LDS (32 KB),
// rows 256..511 in registers (8 uint4/thread). Static LDS 35.3 KB -> 4
// blocks/CU. All d-indexed data in d'-space; STEP==2 output write remaps
// d = 16*(t&3) + (t>>2). (round-0 verified source, unchanged)
template<int STEP>
__global__ __launch_bounds__(256) void k_route(const unsigned short* __restrict__ xh,
                                               const float* __restrict__ b_in,
                                               const float* __restrict__ mz,
                                               float* __restrict__ b_out,
                                               float* __restrict__ outp) {
    __shared__ unsigned short tile[256 * ND];  // 32 KB, rows 0..255
    __shared__ float c_s[NI];
    __shared__ float P[4 * 64];
    __shared__ float o_s[64];

    const int t  = threadIdx.x;
    const int b  = blockIdx.x >> 5;
    const int o  = blockIdx.x & 31;
    const int wv = t >> 6;
    const int l  = t & 63;
    const int dg = t & 7;
    const int ip = t >> 3;

    const unsigned short* gsrc = xh + ((size_t)o * NB + b) * NI * ND;

    // Register half first (latency overlapped by DMA issue + softmax).
    uint4 raw[8];
    #pragma unroll
    for (int k = 0; k < 8; ++k)
        raw[k] = *(const uint4*)(gsrc + (size_t)(256 + 32 * k + ip) * ND + dg * 8);

    // DMA half: wave wv covers 8 KB as 8 x 1-KB instrs (linear layout).
    #pragma unroll
    for (int k = 0; k < 8; ++k)
        GL2LDS(gsrc + wv * 4096 + k * 512 + l * 8, tile + wv * 4096 + k * 512);

    const float* bp = (STEP > 0) ? (b_in + ((size_t)b * NO + o) * NI) : nullptr;
    if (STEP > 0) {
        const float* mrow = mz + (size_t)b * NI;
        const float* zrow = mz + (size_t)(NB * NI) + (size_t)b * NI;
        #pragma unroll
        for (int s = 0; s < 2; ++s) {
            const int i = t + s * 256;
            c_s[i] = __expf(bp[i] - mrow[i]) * zrow[i];
        }
    }
    __syncthreads();                                     // DMA + c_s visible

    // c-weighted accumulation of s[d'] over both halves.
    float acc[8] = {0, 0, 0, 0, 0, 0, 0, 0};
    #pragma unroll
    for (int k = 0; k < 8; ++k) {                        // LDS half, rows 32k+ip
        const int i = 32 * k + ip;
        const uint4 rl = *(const uint4*)(tile + i * ND + dg * 8);
        const float cw = (STEP == 0) ? 0.03125f : c_s[i];
        acc[0] += cw * blo(rl.x); acc[1] += cw * bhi(rl.x);
        acc[2] += cw * blo(rl.y); acc[3] += cw * bhi(rl.y);
        acc[4] += cw * blo(rl.z); acc[5] += cw * bhi(rl.z);
        acc[6] += cw * blo(rl.w); acc[7] += cw * bhi(rl.w);
    }
    #pragma unroll
    for (int k = 0; k < 8; ++k) {                        // register half, rows 256+32k+ip
        const float cw = (STEP == 0) ? 0.03125f : c_s[256 + 32 * k + ip];
        acc[0] += cw * blo(raw[k].x); acc[1] += cw * bhi(raw[k].x);
        acc[2] += cw * blo(raw[k].y); acc[3] += cw * bhi(raw[k].y);
        acc[4] += cw * blo(raw[k].z); acc[5] += cw * bhi(raw[k].z);
        acc[6] += cw * blo(raw[k].w); acc[7] += cw * bhi(raw[k].w);
    }
    #pragma unroll
    for (int j = 0; j < 8; ++j) {          // reduce over ip within wave (bits 3..5)
        acc[j] += __shfl_xor(acc[j], 8);
        acc[j] += __shfl_xor(acc[j], 16);
        acc[j] += __shfl_xor(acc[j], 32);
    }
    if (l < 8) {
        #pragma unroll
        for (int j = 0; j < 8; ++j) P[wv * 64 + l * 8 + j] = acc[j];
    }
    __syncthreads();

    // Wave 0: finish s[d'], squash, emit out vector (o_s in d'-space).
    if (t < 64) {
        const float sv = P[t] + P[64 + t] + P[128 + t] + P[192 + t];
        float s2 = sv * sv;
        #pragma unroll
        for (int m = 1; m < 64; m <<= 1) s2 += __shfl_xor(s2, m);
        const float n = sqrtf(s2);
        const float sc = (s2 / (1.0f + s2)) / (n + 1e-8f);
        const float ov = sv * sc;
        o_s[t] = ov;
        if (STEP == 2) {
            const int d = 16 * (t & 3) + (t >> 2);       // d' -> d remap
            outp[((size_t)b * NO + o) * ND + d] = ov;
        }
    }
    __syncthreads();

    // b-update: dot per row (d'-space), reduce across dg (bits 0..2).
    if (STEP < 2) {
        float oc[8];
        #pragma unroll
        for (int j = 0; j < 8; ++j) oc[j] = o_s[dg * 8 + j];
        float w1 = 0.f, w2 = 0.f;
        #pragma unroll
        for (int k = 0; k < 8; ++k) {                    // LDS half
            const uint4 rl = *(const uint4*)(tile + (32 * k + ip) * ND + dg * 8);
            float pd = blo(rl.x) * oc[0] + bhi(rl.x) * oc[1]
                     + blo(rl.y) * oc[2] + bhi(rl.y) * oc[3]
                     + blo(rl.z) * oc[4] + bhi(rl.z) * oc[5]
                     + blo(rl.w) * oc[6] + bhi(rl.w) * oc[7];
            pd += __shfl_xor(pd, 1);
            pd += __shfl_xor(pd, 2);
            pd += __shfl_xor(pd, 4);
            if (k == dg) w1 = pd;
        }
        #pragma unroll
        for (int k = 0; k < 8; ++k) {                    // register half
            float pd = blo(raw[k].x) * oc[0] + bhi(raw[k].x) * oc[1]
                     + blo(raw[k].y) * oc[2] + bhi(raw[k].y) * oc[3]
                     + blo(raw[k].z) * oc[4] + bhi(raw[k].z) * oc[5]
                     + blo(raw[k].w) * oc[6] + bhi(raw[k].w) * oc[7];
            pd += __shfl_xor(pd, 1);
            pd += __shfl_xor(pd, 2);
            pd += __shfl_xor(pd, 4);
            if (k == dg) w2 = pd;
        }
        const int i1 = 32 * dg + ip;                     // row from LDS half
        const int i2 = 256 + 32 * dg + ip;               // row from register half
        float* bo = b_out + ((size_t)b * NO + o) * NI;
        bo[i1] = ((STEP == 0) ? 0.f : bp[i1]) + w1;
        bo[i2] = ((STEP == 0) ? 0.f : bp[i2]) + w2;
    }
}

extern "C" void kernel_launch(void* const* d_in, const int* in_sizes, int n_in,
                              void* d_out, int out_size, void* d_ws, size_t ws_size,
                              hipStream_t stream) {
    const float* x = (const float*)d_in[0];        // [64,512,64] fp32
    const float* w = (const float*)d_in[1];        // [32,512,64,64] fp32
    float* outp = (float*)d_out;                   // [64,32,64] fp32

    char* ws = (char*)d_ws;
    unsigned short* xh = (unsigned short*)ws;                       // 128 MiB bf16 xh[o][b][i][d']
    float* ba = (float*)(ws + (size_t)134217728);                   // 4 MiB logits A
    float* bb = (float*)(ws + (size_t)134217728 + 4194304);         // 4 MiB logits B
    float* mz = (float*)(ws + (size_t)134217728 + 2 * 4194304);     // 256 KiB m / 1/Z

    k_gemm<<<dim3(2048), dim3(256), 0, stream>>>(x, w, xh);
    k_route<0><<<dim3(2048), dim3(256), 0, stream>>>(xh, nullptr, nullptr, ba, nullptr);
    k_soft<<<dim3(128), dim3(256), 0, stream>>>(ba, mz);
    k_route<1><<<dim3(2048), dim3(256), 0, stream>>>(xh, ba, mz, bb, nullptr);
    k_soft<<<dim3(128), dim3(256), 0, stream>>>(bb, mz);
    k_route<2><<<dim3(2048), dim3(256), 0, stream>>>(xh, bb, mz, nullptr, outp);
}